// Round 1
// baseline (511.002 us; speedup 1.0000x reference)
//
#include <hip/hip_runtime.h>
#include <math.h>

#define B_          1024
#define S_          200
#define H_          128
#define VOCAB_      100000
#define PAD_ID_     99998
#define INTEREST_ID_ 99999

// One block per batch row. 256 threads = 4 waves.
// Phase 1: each wave computes scores for s = wave, wave+4, ... (50 each).
//          Per s: lane l loads float2 at h = 2l (64 lanes cover H=128),
//          tanh(x + key) dot w, wave shuffle-reduce.
// Phase 2: block-wide masked softmax over the 200 scores (LDS).
// Phase 3: scatter-add weights into out[b, id] with global atomicAdd
//          (duplicates of the same token id within a row are possible).
__global__ __launch_bounds__(256) void repeat_decoder_kernel(
    const float* __restrict__ hs,
    const int*   __restrict__ ids,
    const float* __restrict__ w,
    const float* __restrict__ bp,
    float*       __restrict__ out)
{
    __shared__ float s_scores[S_];
    __shared__ float s_red[8];

    const int batch = blockIdx.x;
    const int tid   = threadIdx.x;
    const int wave  = tid >> 6;
    const int lane  = tid & 63;

    const float* hsb = hs + (size_t)batch * (S_ * H_);

    // keys = hs[b, 0, :]; broadcast-added to every s
    const float2 key = ((const float2*)hsb)[lane];
    const float2 wv  = ((const float2*)w)[lane];

    for (int s = wave; s < S_; s += 4) {
        const float2 x = ((const float2*)(hsb + s * H_))[lane];
        float acc = tanhf(x.x + key.x) * wv.x + tanhf(x.y + key.y) * wv.y;
        #pragma unroll
        for (int off = 32; off; off >>= 1)
            acc += __shfl_down(acc, off, 64);
        if (lane == 0) s_scores[s] = acc;
    }
    __syncthreads();

    const float bias = bp[0];
    int   id    = 0;
    bool  valid = false;
    float sc    = -INFINITY;
    if (tid < S_) {
        id    = ids[batch * S_ + tid];
        valid = (id != PAD_ID_) && (id != INTEREST_ID_);
        sc    = valid ? (s_scores[tid] + bias) : -INFINITY;
    }

    // block max (all 256 lanes hold a defined value; -inf for tid >= S_)
    float m = sc;
    #pragma unroll
    for (int off = 32; off; off >>= 1)
        m = fmaxf(m, __shfl_down(m, off, 64));
    if (lane == 0) s_red[wave] = m;
    __syncthreads();
    m = fmaxf(fmaxf(s_red[0], s_red[1]), fmaxf(s_red[2], s_red[3]));

    // block sum of exp
    const float e = (tid < S_ && valid) ? expf(sc - m) : 0.0f;
    float t = e;
    #pragma unroll
    for (int off = 32; off; off >>= 1)
        t += __shfl_down(t, off, 64);
    if (lane == 0) s_red[4 + wave] = t;
    __syncthreads();
    const float sum = s_red[4] + s_red[5] + s_red[6] + s_red[7];

    if (tid < S_ && valid) {
        atomicAdd(&out[(size_t)batch * VOCAB_ + id], e / sum);
    }
}

extern "C" void kernel_launch(void* const* d_in, const int* in_sizes, int n_in,
                              void* d_out, int out_size, void* d_ws, size_t ws_size,
                              hipStream_t stream) {
    const float* hs  = (const float*)d_in[0];
    const int*   ids = (const int*)d_in[1];
    const float* w   = (const float*)d_in[2];
    const float* bp  = (const float*)d_in[3];
    float*       out = (float*)d_out;

    // Zero the 409.6 MB output (poisoned with 0xAA before every launch).
    // Memset node is graph-capturable; completes before the kernel (same stream).
    hipMemsetAsync(d_out, 0, (size_t)out_size * sizeof(float), stream);

    repeat_decoder_kernel<<<B_, 256, 0, stream>>>(hs, ids, w, bp, out);
}

// Round 2
// 496.348 us; speedup vs baseline: 1.0295x; 1.0295x over previous
//
#include <hip/hip_runtime.h>
#include <math.h>

#define B_           1024
#define S_           200
#define H_           128
#define VOCAB_       100000
#define PAD_ID_      99998
#define INTEREST_ID_ 99999
#define NTHREADS_    512   // 8 waves/block; 1024 blocks -> 4 blocks/CU = 32 waves/CU

// One block per batch row. Fuses:
//   1. score compute:  scores[s] = tanh(hs[b,s,:] + hs[b,0,:]) . w   (wave handles
//      2 rows/iter: half-wave per row, float4/lane, 5-step xor-shuffle reduce)
//   2. zero-fill of out[b, 0:VOCAB] with float4 stores (this block owns the row,
//      so no memset dispatch is needed)
//   3. masked softmax over the 200 scores
//   4. scatter: atomicAdd(out[b, id_s], weight_s)  -- after __syncthreads, which
//      drains the zero stores (vmcnt(0) before s_barrier); atomics resolve at the
//      same L2 the stores landed in, and only this block touches this row.
__global__ __launch_bounds__(NTHREADS_) void repeat_decoder_fused(
    const float* __restrict__ hs,
    const int*   __restrict__ ids,
    const float* __restrict__ w,
    const float* __restrict__ bp,
    float*       __restrict__ out)
{
    __shared__ float s_scores[S_];
    __shared__ float s_red[16];

    const int batch = blockIdx.x;
    const int tid   = threadIdx.x;
    const int wave  = tid >> 6;
    const int lane  = tid & 63;
    const int half  = lane >> 5;   // which of the 2 rows this half-wave handles
    const int hl    = lane & 31;   // lane within half: covers h = hl*4 .. hl*4+3

    const float* hsb  = hs + (size_t)batch * (S_ * H_);
    float*       rowo = out + (size_t)batch * VOCAB_;

    // Per-lane constants: key = hs[b,0,h..h+3], wv = w[h..h+3]
    const float4 key = ((const float4*)hsb)[hl];
    const float4 wv  = ((const float4*)w)[hl];

    // ---- Phase 1: scores. 8 waves x 2 rows/iter = 16 rows per sweep ----
    for (int s0 = wave * 2; s0 < S_; s0 += 16) {
        const int s = s0 + half;                      // always < 200
        const float4 x = ((const float4*)(hsb + s * H_))[hl];
        float acc = tanhf(x.x + key.x) * wv.x
                  + tanhf(x.y + key.y) * wv.y
                  + tanhf(x.z + key.z) * wv.z
                  + tanhf(x.w + key.w) * wv.w;
        // reduce across the 32 lanes of this half (xor masks < 32 stay in-half)
        #pragma unroll
        for (int off = 16; off; off >>= 1)
            acc += __shfl_xor(acc, off, 64);
        if (hl == 0) s_scores[s] = acc;
    }

    // ---- Phase 2: zero this block's output row (25000 float4 = 400 KB) ----
    {
        float4* rowo4 = (float4*)rowo;
        const float4 z = make_float4(0.f, 0.f, 0.f, 0.f);
        #pragma unroll 4
        for (int i = tid; i < VOCAB_ / 4; i += NTHREADS_)
            rowo4[i] = z;
    }

    __syncthreads();   // scores visible in LDS; zero stores drained to L2

    // ---- Phase 3: masked softmax over 200 scores (all 8 waves participate) ----
    const float bias = bp[0];
    int   id    = 0;
    bool  valid = false;
    float sc    = -INFINITY;
    if (tid < S_) {
        id    = ids[batch * S_ + tid];
        valid = (id != PAD_ID_) && (id != INTEREST_ID_);
        sc    = valid ? (s_scores[tid] + bias) : -INFINITY;
    }

    float m = sc;
    #pragma unroll
    for (int off = 32; off; off >>= 1)
        m = fmaxf(m, __shfl_down(m, off, 64));
    if (lane == 0) s_red[wave] = m;
    __syncthreads();
    m = fmaxf(fmaxf(fmaxf(s_red[0], s_red[1]), fmaxf(s_red[2], s_red[3])),
              fmaxf(fmaxf(s_red[4], s_red[5]), fmaxf(s_red[6], s_red[7])));

    const float e = valid ? expf(sc - m) : 0.0f;
    float t = e;
    #pragma unroll
    for (int off = 32; off; off >>= 1)
        t += __shfl_down(t, off, 64);
    if (lane == 0) s_red[8 + wave] = t;
    __syncthreads();
    const float sum = (s_red[8]  + s_red[9])  + (s_red[10] + s_red[11])
                    + (s_red[12] + s_red[13]) + (s_red[14] + s_red[15]);

    // ---- Phase 4: scatter (duplicate ids possible -> atomicAdd) ----
    if (valid) {
        atomicAdd(&rowo[id], e / sum);
    }
}

extern "C" void kernel_launch(void* const* d_in, const int* in_sizes, int n_in,
                              void* d_out, int out_size, void* d_ws, size_t ws_size,
                              hipStream_t stream) {
    const float* hs  = (const float*)d_in[0];
    const int*   ids = (const int*)d_in[1];
    const float* w   = (const float*)d_in[2];
    const float* bp  = (const float*)d_in[3];
    float*       out = (float*)d_out;

    repeat_decoder_fused<<<B_, NTHREADS_, 0, stream>>>(hs, ids, w, bp, out);
}